// Round 1
// baseline (950.785 us; speedup 1.0000x reference)
//
#include <hip/hip_runtime.h>
#include <math.h>

#define D_FEAT 32

// Sign-magnitude punning: for IEEE floats (no NaN), integer compare on the
// bit pattern matches float order for v>=0 (signed int) and reverses for v<0
// (unsigned int). Standard float atomic min/max trick.
__device__ __forceinline__ void atomicMaxF(float* addr, float v) {
    if (v >= 0.0f) atomicMax((int*)addr, __float_as_int(v));
    else           atomicMin((unsigned int*)addr, __float_as_uint(v));
}
__device__ __forceinline__ void atomicMinF(float* addr, float v) {
    if (v >= 0.0f) atomicMin((int*)addr, __float_as_int(v));
    else           atomicMax((unsigned int*)addr, __float_as_uint(v));
}

// ws layout (floats): [0,ND) sum | [ND,2ND) min | [2ND,3ND) max | [3ND,3ND+N) deg
__global__ void init_kernel(float* __restrict__ ws, int ND, int N) {
    int i = blockIdx.x * blockDim.x + threadIdx.x;
    int total = 3 * ND + N;
    if (i >= total) return;
    float v;
    if      (i <     ND) v = 0.0f;       // sum
    else if (i < 2 * ND) v =  INFINITY;  // min identity
    else if (i < 3 * ND) v = -INFINITY;  // max identity
    else                 v = 0.0f;       // deg
    ws[i] = v;
}

__global__ void scatter_kernel(const float* __restrict__ m,
                               const int*   __restrict__ dst,
                               float* __restrict__ sum_, float* __restrict__ mn_,
                               float* __restrict__ mx_,  float* __restrict__ deg_,
                               int E) {
    int gid = blockIdx.x * blockDim.x + threadIdx.x;   // E*D = 51.2M < 2^31
    if (gid >= E * D_FEAT) return;
    int e = gid >> 5;          // edge
    int f = gid & 31;          // feature
    float v  = m[gid];         // fully coalesced
    int node = dst[e];         // 32 lanes broadcast same address
    int base = node * D_FEAT + f;
    atomicAdd(&sum_[base], v);
    atomicMinF(&mn_[base], v);
    atomicMaxF(&mx_[base], v);
    if (f == 0) atomicAdd(&deg_[node], 1.0f);
}

__global__ void finalize_kernel(const float* __restrict__ sum_,
                                const float* __restrict__ mn_,
                                const float* __restrict__ mx_,
                                const float* __restrict__ deg_,
                                const float* __restrict__ w,
                                const float* __restrict__ b,
                                float* __restrict__ out, int ND) {
    int gid = blockIdx.x * blockDim.x + threadIdx.x;
    if (gid >= ND) return;
    int n = gid >> 5;
    float s = sum_[gid];
    float d = deg_[n];
    bool has = d > 0.0f;
    float mnv = has ? mn_[gid] : 0.0f;
    float mxv = has ? mx_[gid] : 0.0f;
    float mean = s / fmaxf(d, 1.0f);
    out[gid] = w[0] * s + w[1] * mnv + w[2] * mxv + w[3] * mean + b[0];
}

extern "C" void kernel_launch(void* const* d_in, const int* in_sizes, int n_in,
                              void* d_out, int out_size, void* d_ws, size_t ws_size,
                              hipStream_t stream) {
    const float* m   = (const float*)d_in[0];
    const int*   dst = (const int*)  d_in[1];
    const float* w   = (const float*)d_in[2];
    const float* b   = (const float*)d_in[3];

    int E  = in_sizes[0] / D_FEAT;   // 1,600,000
    int N  = out_size    / D_FEAT;   // 50,000
    int ND = N * D_FEAT;             // 1,600,000

    float* ws   = (float*)d_ws;
    float* sum_ = ws;
    float* mn_  = ws + ND;
    float* mx_  = ws + 2 * ND;
    float* deg_ = ws + 3 * ND;

    int initTotal = 3 * ND + N;
    hipLaunchKernelGGL(init_kernel, dim3((initTotal + 255) / 256), dim3(256), 0, stream,
                       ws, ND, N);

    long long scatterThreads = (long long)E * D_FEAT;
    hipLaunchKernelGGL(scatter_kernel, dim3((unsigned)((scatterThreads + 255) / 256)), dim3(256), 0, stream,
                       m, dst, sum_, mn_, mx_, deg_, E);

    hipLaunchKernelGGL(finalize_kernel, dim3((ND + 255) / 256), dim3(256), 0, stream,
                       sum_, mn_, mx_, deg_, w, b, (float*)d_out, ND);
}

// Round 2
// 509.279 us; speedup vs baseline: 1.8669x; 1.8669x over previous
//
#include <hip/hip_runtime.h>
#include <math.h>

#define D_FEAT 32

// ---------------- histogram ----------------
__global__ void hist_kernel(const int* __restrict__ dst, int* __restrict__ counts, int E) {
    int e = blockIdx.x * blockDim.x + threadIdx.x;
    if (e < E) atomicAdd(&counts[dst[e]], 1);
}

// ---------------- scan (3 stages) ----------------
// stage 1: per-block (2048 elems) exclusive scan + block sums
__global__ void scan1_kernel(const int* __restrict__ counts, int* __restrict__ scanned,
                             int* __restrict__ blockSums, int N) {
    __shared__ int lds[256];
    int tid = threadIdx.x;
    int base = blockIdx.x * 2048 + tid * 8;
    int vals[8];
    int s = 0;
    #pragma unroll
    for (int k = 0; k < 8; k++) {
        int idx = base + k;
        vals[k] = (idx < N) ? counts[idx] : 0;
        s += vals[k];
    }
    lds[tid] = s;
    __syncthreads();
    // Hillis-Steele inclusive scan over 256 thread-sums
    for (int off = 1; off < 256; off <<= 1) {
        int t = (tid >= off) ? lds[tid - off] : 0;
        __syncthreads();
        lds[tid] += t;
        __syncthreads();
    }
    int ex = lds[tid] - s;   // exclusive prefix of this thread within block
    if (tid == 255) blockSums[blockIdx.x] = lds[255];
    int run = ex;
    #pragma unroll
    for (int k = 0; k < 8; k++) {
        int idx = base + k;
        if (idx < N) scanned[idx] = run;
        run += vals[k];
    }
}

// stage 2: serial exclusive scan of block sums (nb ~ 25, trivial)
__global__ void scan2_kernel(int* __restrict__ blockSums, int nb) {
    if (blockIdx.x == 0 && threadIdx.x == 0) {
        int acc = 0;
        for (int i = 0; i < nb; i++) {
            int t = blockSums[i];
            blockSums[i] = acc;
            acc += t;
        }
    }
}

// stage 3: add block offsets; init offsets[] and cursor[]
__global__ void scan3_kernel(const int* __restrict__ scanned, const int* __restrict__ blockSums,
                             int* __restrict__ offsets, int* __restrict__ cursor,
                             int N, int E) {
    int i = blockIdx.x * blockDim.x + threadIdx.x;
    if (i < N) {
        int off = scanned[i] + blockSums[i >> 11];  // 2048 per scan1 block
        offsets[i] = off;
        cursor[i]  = off;
    }
    if (i == 0) offsets[N] = E;
}

// ---------------- scatter edge ids into segment order ----------------
__global__ void scatter_ids_kernel(const int* __restrict__ dst, int* __restrict__ cursor,
                                   int* __restrict__ eid, int E) {
    int e = blockIdx.x * blockDim.x + threadIdx.x;
    if (e < E) {
        int pos = atomicAdd(&cursor[dst[e]], 1);
        eid[pos] = e;
    }
}

// ---------------- gather-reduce + finalize ----------------
// 32 lanes per node (lane = feature), 8 nodes per 256-thread block.
__global__ void gather_reduce_kernel(const float* __restrict__ m,
                                     const int* __restrict__ eid,
                                     const int* __restrict__ offsets,
                                     const float* __restrict__ w,
                                     const float* __restrict__ b,
                                     float* __restrict__ out, int N) {
    int node = blockIdx.x * 8 + (threadIdx.x >> 5);
    int f = threadIdx.x & 31;
    if (node >= N) return;
    int start = offsets[node];
    int end   = offsets[node + 1];

    float s = 0.0f, mn = INFINITY, mx = -INFINITY;

    for (int base = start; base < end; base += 32) {
        int cnt = end - base;
        if (cnt > 32) cnt = 32;
        // coalesced block-load of up to 32 edge ids; broadcast via shfl
        int e = (f < cnt) ? eid[base + f] : 0;
        int j = 0;
        for (; j + 4 <= cnt; j += 4) {
            int e0 = __shfl(e, j,     32);
            int e1 = __shfl(e, j + 1, 32);
            int e2 = __shfl(e, j + 2, 32);
            int e3 = __shfl(e, j + 3, 32);
            float v0 = m[e0 * D_FEAT + f];
            float v1 = m[e1 * D_FEAT + f];
            float v2 = m[e2 * D_FEAT + f];
            float v3 = m[e3 * D_FEAT + f];
            s += v0; mn = fminf(mn, v0); mx = fmaxf(mx, v0);
            s += v1; mn = fminf(mn, v1); mx = fmaxf(mx, v1);
            s += v2; mn = fminf(mn, v2); mx = fmaxf(mx, v2);
            s += v3; mn = fminf(mn, v3); mx = fmaxf(mx, v3);
        }
        for (; j < cnt; j++) {
            int ej = __shfl(e, j, 32);
            float v = m[ej * D_FEAT + f];
            s += v; mn = fminf(mn, v); mx = fmaxf(mx, v);
        }
    }

    int deg = end - start;
    bool has = deg > 0;
    float mean = s / fmaxf((float)deg, 1.0f);
    float mnv = has ? mn : 0.0f;
    float mxv = has ? mx : 0.0f;
    out[node * D_FEAT + f] = w[0] * s + w[1] * mnv + w[2] * mxv + w[3] * mean + b[0];
}

extern "C" void kernel_launch(void* const* d_in, const int* in_sizes, int n_in,
                              void* d_out, int out_size, void* d_ws, size_t ws_size,
                              hipStream_t stream) {
    const float* m   = (const float*)d_in[0];
    const int*   dst = (const int*)  d_in[1];
    const float* w   = (const float*)d_in[2];
    const float* b   = (const float*)d_in[3];

    int E = in_sizes[0] / D_FEAT;   // 1,600,000
    int N = out_size    / D_FEAT;   // 50,000

    // ws layout (ints)
    int* ws        = (int*)d_ws;
    int* counts    = ws;                  // N
    int* scanned   = counts + N;          // N
    int* blockSums = scanned + N;         // <=64
    int* offsets   = blockSums + 64;      // N+1
    int* cursor    = offsets + (N + 1);   // N
    int* eid       = cursor + N;          // E

    int nbScan = (N + 2047) / 2048;       // 25

    hipMemsetAsync(counts, 0, (size_t)N * sizeof(int), stream);

    hipLaunchKernelGGL(hist_kernel, dim3((E + 255) / 256), dim3(256), 0, stream,
                       dst, counts, E);
    hipLaunchKernelGGL(scan1_kernel, dim3(nbScan), dim3(256), 0, stream,
                       counts, scanned, blockSums, N);
    hipLaunchKernelGGL(scan2_kernel, dim3(1), dim3(64), 0, stream,
                       blockSums, nbScan);
    hipLaunchKernelGGL(scan3_kernel, dim3((N + 255) / 256), dim3(256), 0, stream,
                       scanned, blockSums, offsets, cursor, N, E);
    hipLaunchKernelGGL(scatter_ids_kernel, dim3((E + 255) / 256), dim3(256), 0, stream,
                       dst, cursor, eid, E);
    hipLaunchKernelGGL(gather_reduce_kernel, dim3((N + 7) / 8), dim3(256), 0, stream,
                       m, eid, offsets, w, b, (float*)d_out, N);
}

// Round 3
// 357.705 us; speedup vs baseline: 2.6580x; 1.4237x over previous
//
#include <hip/hip_runtime.h>
#include <math.h>

#define D_FEAT 32
#define BSHIFT 6                 // 64 nodes per bucket
#define NODES_PER_BKT 64
#define TILE 8192
#define PT 32                    // TILE / 256
#define MAXBKT 1024              // >= 782, pow2 for LDS arrays
#define CAP 4096                 // bucket edge capacity (mean 2048, Poisson tail)

// ---------------- K1: bucket histogram ----------------
__global__ void hist_kernel(const int* __restrict__ dst, int* __restrict__ bucketCount,
                            int E, int nbucket) {
    __shared__ int h[MAXBKT];
    for (int i = threadIdx.x; i < nbucket; i += 256) h[i] = 0;
    __syncthreads();
    int tbase = blockIdx.x * TILE;
    #pragma unroll 4
    for (int k = 0; k < PT; k++) {
        int e = tbase + k * 256 + threadIdx.x;
        if (e < E) atomicAdd(&h[dst[e] >> BSHIFT], 1);
    }
    __syncthreads();
    for (int i = threadIdx.x; i < nbucket; i += 256) {
        int c = h[i];
        if (c) atomicAdd(&bucketCount[i], c);
    }
}

// ---------------- K2: scan bucket counts -> bases + cursors ----------------
__global__ void scan_kernel(const int* __restrict__ bucketCount,
                            int* __restrict__ bucketBase, int* __restrict__ bucketCursor,
                            int nbucket, int E) {
    __shared__ int lds[256];
    int tid = threadIdx.x;
    int vals[4];
    int s = 0;
    #pragma unroll
    for (int k = 0; k < 4; k++) {
        int i = tid * 4 + k;
        vals[k] = (i < nbucket) ? bucketCount[i] : 0;
        s += vals[k];
    }
    lds[tid] = s;
    __syncthreads();
    for (int off = 1; off < 256; off <<= 1) {
        int t = (tid >= off) ? lds[tid - off] : 0;
        __syncthreads();
        lds[tid] += t;
        __syncthreads();
    }
    int run = lds[tid] - s;   // exclusive prefix
    #pragma unroll
    for (int k = 0; k < 4; k++) {
        int i = tid * 4 + k;
        if (i < nbucket) { bucketBase[i] = run; bucketCursor[i] = run; }
        run += vals[k];
    }
    if (tid == 0) bucketBase[nbucket] = E;
}

// ---------------- K3: partition edges into buckets (packed keys) ----------------
// key = (dst & 63) << 26 | eid      (eid < 2^21, local node 6 bits)
__global__ void partition_kernel(const int* __restrict__ dst,
                                 int* __restrict__ bucketCursor,
                                 unsigned int* __restrict__ keys,
                                 int E, int nbucket) {
    __shared__ int h[MAXBKT];
    __shared__ int baseL[MAXBKT];
    int tid = threadIdx.x;
    for (int i = tid; i < nbucket; i += 256) h[i] = 0;
    __syncthreads();
    int tbase = blockIdx.x * TILE;
    int pk[PT];                       // (bucket << 13) | rank
    #pragma unroll 4
    for (int k = 0; k < PT; k++) {
        int e = tbase + k * 256 + tid;
        if (e < E) {
            int b = dst[e] >> BSHIFT;
            int r = atomicAdd(&h[b], 1);
            pk[k] = (b << 13) | r;
        } else pk[k] = -1;
    }
    __syncthreads();
    for (int i = tid; i < nbucket; i += 256) {
        int c = h[i];
        baseL[i] = c ? atomicAdd(&bucketCursor[i], c) : 0;
    }
    __syncthreads();
    #pragma unroll 4
    for (int k = 0; k < PT; k++) {
        if (pk[k] >= 0) {
            int e = tbase + k * 256 + tid;
            int d = dst[e];                        // L1/L2-hot re-read
            int b = pk[k] >> 13;
            int r = pk[k] & 8191;
            keys[baseL[b] + r] = ((unsigned)(d & (NODES_PER_BKT - 1)) << 26) | (unsigned)e;
        }
    }
}

// ---------------- K4: fused bucket-sort (in LDS) + gather-reduce + finalize ----------------
__global__ void bucket_gather_kernel(const float* __restrict__ m,
                                     const unsigned int* __restrict__ keys,
                                     const int* __restrict__ bucketBase,
                                     const float* __restrict__ w,
                                     const float* __restrict__ bia,
                                     float* __restrict__ out, int N) {
    __shared__ int nh[NODES_PER_BKT];
    __shared__ int noff[NODES_PER_BKT + 1];
    __shared__ int ncur[NODES_PER_BKT];
    __shared__ int seid[CAP];
    int bkt = blockIdx.x;
    int tid = threadIdx.x;
    int start = bucketBase[bkt];
    int cnt = bucketBase[bkt + 1] - start;
    if (cnt > CAP) cnt = CAP;        // statistically impossible; OOB guard

    if (tid < NODES_PER_BKT) nh[tid] = 0;
    __syncthreads();
    for (int i = tid; i < cnt; i += 256)
        atomicAdd(&nh[keys[start + i] >> 26], 1);
    __syncthreads();
    if (tid < NODES_PER_BKT) {        // lanes 0..63 of wave 0: full-wave scan
        int v = nh[tid];
        int x = v;
        #pragma unroll
        for (int off = 1; off < 64; off <<= 1) {
            int t = __shfl_up(x, off, 64);
            if (tid >= off) x += t;
        }
        noff[tid + 1] = x;
        if (tid == 0) noff[0] = 0;
        ncur[tid] = x - v;            // exclusive
    }
    __syncthreads();
    for (int i = tid; i < cnt; i += 256) {
        unsigned int k = keys[start + i];
        int pos = atomicAdd(&ncur[k >> 26], 1);
        seid[pos] = (int)(k & 0x03FFFFFFu);
    }
    __syncthreads();

    // gather: half-wave per node, lane = feature
    int hw = tid >> 5;
    int f  = tid & 31;
    int nodeBase = bkt << BSHIFT;
    float w0 = w[0], w1 = w[1], w2 = w[2], w3 = w[3], bb = bia[0];
    for (int nl = hw; nl < NODES_PER_BKT; nl += 8) {
        int node = nodeBase + nl;
        if (node >= N) break;
        int s0 = noff[nl], e0 = noff[nl + 1];
        int deg = e0 - s0;
        float s = 0.0f, mn = INFINITY, mx = -INFINITY;
        int j = s0;
        for (; j + 4 <= e0; j += 4) {
            int e0i = seid[j], e1i = seid[j + 1], e2i = seid[j + 2], e3i = seid[j + 3];
            float v0 = m[e0i * D_FEAT + f];
            float v1 = m[e1i * D_FEAT + f];
            float v2 = m[e2i * D_FEAT + f];
            float v3 = m[e3i * D_FEAT + f];
            s += v0; mn = fminf(mn, v0); mx = fmaxf(mx, v0);
            s += v1; mn = fminf(mn, v1); mx = fmaxf(mx, v1);
            s += v2; mn = fminf(mn, v2); mx = fmaxf(mx, v2);
            s += v3; mn = fminf(mn, v3); mx = fmaxf(mx, v3);
        }
        for (; j < e0; j++) {
            float v = m[seid[j] * D_FEAT + f];
            s += v; mn = fminf(mn, v); mx = fmaxf(mx, v);
        }
        bool has = deg > 0;
        float mean = s / fmaxf((float)deg, 1.0f);
        out[node * D_FEAT + f] = w0 * s + w1 * (has ? mn : 0.0f)
                               + w2 * (has ? mx : 0.0f) + w3 * mean + bb;
    }
}

extern "C" void kernel_launch(void* const* d_in, const int* in_sizes, int n_in,
                              void* d_out, int out_size, void* d_ws, size_t ws_size,
                              hipStream_t stream) {
    const float* m   = (const float*)d_in[0];
    const int*   dst = (const int*)  d_in[1];
    const float* w   = (const float*)d_in[2];
    const float* b   = (const float*)d_in[3];

    int E = in_sizes[0] / D_FEAT;           // 1,600,000
    int N = out_size    / D_FEAT;           // 50,000
    int nbucket = (N + NODES_PER_BKT - 1) >> BSHIFT;   // 782

    int* ws           = (int*)d_ws;
    int* bucketCount  = ws;                             // MAXBKT
    int* bucketBase   = bucketCount + MAXBKT;           // MAXBKT+1
    int* bucketCursor = bucketBase + MAXBKT + 1;        // MAXBKT
    unsigned int* keys = (unsigned int*)(bucketCursor + MAXBKT);   // E

    int nTiles = (E + TILE - 1) / TILE;     // 196

    hipMemsetAsync(bucketCount, 0, MAXBKT * sizeof(int), stream);
    hipLaunchKernelGGL(hist_kernel, dim3(nTiles), dim3(256), 0, stream,
                       dst, bucketCount, E, nbucket);
    hipLaunchKernelGGL(scan_kernel, dim3(1), dim3(256), 0, stream,
                       bucketCount, bucketBase, bucketCursor, nbucket, E);
    hipLaunchKernelGGL(partition_kernel, dim3(nTiles), dim3(256), 0, stream,
                       dst, bucketCursor, keys, E, nbucket);
    hipLaunchKernelGGL(bucket_gather_kernel, dim3(nbucket), dim3(256), 0, stream,
                       m, keys, bucketBase, w, b, (float*)d_out, N);
}

// Round 4
// 338.073 us; speedup vs baseline: 2.8124x; 1.0581x over previous
//
#include <hip/hip_runtime.h>
#include <math.h>

#define D_FEAT 32
#define BSHIFT 6                 // 64 nodes per bucket
#define NODES_PER_BKT 64
#define TILE 8192
#define PT 32                    // edges per thread (TILE / 256)
#define MAXBKT 1024              // >= 782, pow2 for LDS arrays
#define CAP 4096                 // bucket edge capacity (mean 2048, ~45 sigma guard)

// ---------------- K1: bucket histogram (int4 loads) ----------------
__global__ void hist_kernel(const int* __restrict__ dst, int* __restrict__ bucketCount,
                            int E4, int nbucket) {
    __shared__ int h[MAXBKT];
    for (int i = threadIdx.x; i < nbucket; i += 256) h[i] = 0;
    __syncthreads();
    const int4* dst4 = (const int4*)dst;
    int tbase4 = blockIdx.x * (TILE / 4);
    #pragma unroll
    for (int k = 0; k < PT / 4; k++) {
        int i4 = tbase4 + k * 256 + threadIdx.x;
        if (i4 < E4) {
            int4 d = dst4[i4];
            atomicAdd(&h[d.x >> BSHIFT], 1);
            atomicAdd(&h[d.y >> BSHIFT], 1);
            atomicAdd(&h[d.z >> BSHIFT], 1);
            atomicAdd(&h[d.w >> BSHIFT], 1);
        }
    }
    __syncthreads();
    for (int i = threadIdx.x; i < nbucket; i += 256) {
        int c = h[i];
        if (c) atomicAdd(&bucketCount[i], c);
    }
}

// ---------------- K2: scan bucket counts -> bases + cursors ----------------
__global__ void scan_kernel(const int* __restrict__ bucketCount,
                            int* __restrict__ bucketBase, int* __restrict__ bucketCursor,
                            int nbucket, int E) {
    __shared__ int lds[256];
    int tid = threadIdx.x;
    int vals[4];
    int s = 0;
    #pragma unroll
    for (int k = 0; k < 4; k++) {
        int i = tid * 4 + k;
        vals[k] = (i < nbucket) ? bucketCount[i] : 0;
        s += vals[k];
    }
    lds[tid] = s;
    __syncthreads();
    for (int off = 1; off < 256; off <<= 1) {
        int t = (tid >= off) ? lds[tid - off] : 0;
        __syncthreads();
        lds[tid] += t;
        __syncthreads();
    }
    int run = lds[tid] - s;   // exclusive prefix
    #pragma unroll
    for (int k = 0; k < 4; k++) {
        int i = tid * 4 + k;
        if (i < nbucket) { bucketBase[i] = run; bucketCursor[i] = run; }
        run += vals[k];
    }
    if (tid == 0) bucketBase[nbucket] = E;
}

// ---------------- K3: partition edges into buckets (packed keys) ----------------
// pk = (b << 19) | (localnode << 13) | rank   (b<1024, local<64, rank<8192)
// key = localnode << 26 | eid                 (eid < 2^21)
__global__ void partition_kernel(const int* __restrict__ dst,
                                 int* __restrict__ bucketCursor,
                                 unsigned int* __restrict__ keys,
                                 int E4, int nbucket) {
    __shared__ int h[MAXBKT];
    __shared__ int baseL[MAXBKT];
    int tid = threadIdx.x;
    for (int i = tid; i < nbucket; i += 256) h[i] = 0;
    __syncthreads();
    const int4* dst4 = (const int4*)dst;
    int tbase4 = blockIdx.x * (TILE / 4);
    int pk[PT];
    #pragma unroll
    for (int k = 0; k < PT / 4; k++) {
        int i4 = tbase4 + k * 256 + tid;
        if (i4 < E4) {
            int4 d = dst4[i4];
            int b0 = d.x >> BSHIFT; int r0 = atomicAdd(&h[b0], 1);
            int b1 = d.y >> BSHIFT; int r1 = atomicAdd(&h[b1], 1);
            int b2 = d.z >> BSHIFT; int r2 = atomicAdd(&h[b2], 1);
            int b3 = d.w >> BSHIFT; int r3 = atomicAdd(&h[b3], 1);
            pk[4 * k + 0] = (b0 << 19) | ((d.x & 63) << 13) | r0;
            pk[4 * k + 1] = (b1 << 19) | ((d.y & 63) << 13) | r1;
            pk[4 * k + 2] = (b2 << 19) | ((d.z & 63) << 13) | r2;
            pk[4 * k + 3] = (b3 << 19) | ((d.w & 63) << 13) | r3;
        } else {
            pk[4 * k + 0] = -1; pk[4 * k + 1] = -1;
            pk[4 * k + 2] = -1; pk[4 * k + 3] = -1;
        }
    }
    __syncthreads();
    for (int i = tid; i < nbucket; i += 256) {
        int c = h[i];
        baseL[i] = c ? atomicAdd(&bucketCursor[i], c) : 0;
    }
    __syncthreads();
    #pragma unroll
    for (int k = 0; k < PT / 4; k++) {
        int i4 = tbase4 + k * 256 + tid;
        int e = i4 * 4;
        #pragma unroll
        for (int l = 0; l < 4; l++) {
            int p = pk[4 * k + l];
            if (p >= 0) {
                int b   = p >> 19;
                int loc = (p >> 13) & 63;
                int r   = p & 8191;
                keys[baseL[b] + r] = ((unsigned)loc << 26) | (unsigned)(e + l);
            }
        }
    }
}

// ---------------- K4: fused bucket-sort (LDS) + gather-reduce + finalize ----------------
__global__ __launch_bounds__(256) void bucket_gather_kernel(
        const float* __restrict__ m,
        const unsigned int* __restrict__ keys,
        const int* __restrict__ bucketBase,
        const float* __restrict__ w,
        const float* __restrict__ bia,
        float* __restrict__ out, int N) {
    __shared__ unsigned int ukey[CAP];
    __shared__ int seid[CAP];
    __shared__ int nh[NODES_PER_BKT];
    __shared__ int noff[NODES_PER_BKT + 1];
    __shared__ int ncur[NODES_PER_BKT];
    int bkt = blockIdx.x;
    int tid = threadIdx.x;
    int start = bucketBase[bkt];
    int cnt = bucketBase[bkt + 1] - start;
    if (cnt > CAP) cnt = CAP;        // statistically impossible; OOB guard

    if (tid < NODES_PER_BKT) nh[tid] = 0;
    __syncthreads();
    for (int i = tid; i < cnt; i += 256) {
        unsigned int k = keys[start + i];   // single global read of keys
        ukey[i] = k;
        atomicAdd(&nh[k >> 26], 1);
    }
    __syncthreads();
    if (tid < NODES_PER_BKT) {            // lanes 0..63 of wave 0: full-wave scan
        int v = nh[tid];
        int x = v;
        #pragma unroll
        for (int off = 1; off < 64; off <<= 1) {
            int t = __shfl_up(x, off, 64);
            if (tid >= off) x += t;
        }
        noff[tid + 1] = x;
        if (tid == 0) noff[0] = 0;
        ncur[tid] = x - v;                // exclusive
    }
    __syncthreads();
    for (int i = tid; i < cnt; i += 256) {
        unsigned int k = ukey[i];
        int pos = atomicAdd(&ncur[k >> 26], 1);
        seid[pos] = (int)(k & 0x03FFFFFFu);
    }
    __syncthreads();

    // gather: half-wave per node, lane = feature, 8 rows in flight
    int hw = tid >> 5;
    int f  = tid & 31;
    int nodeBase = bkt << BSHIFT;
    float w0 = w[0], w1 = w[1], w2 = w[2], w3 = w[3], bb = bia[0];
    for (int nl = hw; nl < NODES_PER_BKT; nl += 8) {
        int node = nodeBase + nl;
        if (node >= N) break;
        int s0 = noff[nl], e0 = noff[nl + 1];
        int deg = e0 - s0;
        float s = 0.0f, mn = INFINITY, mx = -INFINITY;
        int j = s0;
        for (; j + 8 <= e0; j += 8) {
            float v0 = m[seid[j]     * D_FEAT + f];
            float v1 = m[seid[j + 1] * D_FEAT + f];
            float v2 = m[seid[j + 2] * D_FEAT + f];
            float v3 = m[seid[j + 3] * D_FEAT + f];
            float v4 = m[seid[j + 4] * D_FEAT + f];
            float v5 = m[seid[j + 5] * D_FEAT + f];
            float v6 = m[seid[j + 6] * D_FEAT + f];
            float v7 = m[seid[j + 7] * D_FEAT + f];
            s += v0; mn = fminf(mn, v0); mx = fmaxf(mx, v0);
            s += v1; mn = fminf(mn, v1); mx = fmaxf(mx, v1);
            s += v2; mn = fminf(mn, v2); mx = fmaxf(mx, v2);
            s += v3; mn = fminf(mn, v3); mx = fmaxf(mx, v3);
            s += v4; mn = fminf(mn, v4); mx = fmaxf(mx, v4);
            s += v5; mn = fminf(mn, v5); mx = fmaxf(mx, v5);
            s += v6; mn = fminf(mn, v6); mx = fmaxf(mx, v6);
            s += v7; mn = fminf(mn, v7); mx = fmaxf(mx, v7);
        }
        for (; j < e0; j++) {
            float v = m[seid[j] * D_FEAT + f];
            s += v; mn = fminf(mn, v); mx = fmaxf(mx, v);
        }
        bool has = deg > 0;
        float mean = s / fmaxf((float)deg, 1.0f);
        out[node * D_FEAT + f] = w0 * s + w1 * (has ? mn : 0.0f)
                               + w2 * (has ? mx : 0.0f) + w3 * mean + bb;
    }
}

extern "C" void kernel_launch(void* const* d_in, const int* in_sizes, int n_in,
                              void* d_out, int out_size, void* d_ws, size_t ws_size,
                              hipStream_t stream) {
    const float* m   = (const float*)d_in[0];
    const int*   dst = (const int*)  d_in[1];
    const float* w   = (const float*)d_in[2];
    const float* b   = (const float*)d_in[3];

    int E = in_sizes[0] / D_FEAT;           // 1,600,000
    int N = out_size    / D_FEAT;           // 50,000
    int E4 = E / 4;                          // E is divisible by 4
    int nbucket = (N + NODES_PER_BKT - 1) >> BSHIFT;   // 782

    int* ws           = (int*)d_ws;
    int* bucketCount  = ws;                             // MAXBKT
    int* bucketBase   = bucketCount + MAXBKT;           // MAXBKT+1
    int* bucketCursor = bucketBase + MAXBKT + 1;        // MAXBKT
    unsigned int* keys = (unsigned int*)(bucketCursor + MAXBKT);   // E

    int nTiles = (E + TILE - 1) / TILE;     // 196

    hipMemsetAsync(bucketCount, 0, MAXBKT * sizeof(int), stream);
    hipLaunchKernelGGL(hist_kernel, dim3(nTiles), dim3(256), 0, stream,
                       dst, bucketCount, E4, nbucket);
    hipLaunchKernelGGL(scan_kernel, dim3(1), dim3(256), 0, stream,
                       bucketCount, bucketBase, bucketCursor, nbucket, E);
    hipLaunchKernelGGL(partition_kernel, dim3(nTiles), dim3(256), 0, stream,
                       dst, bucketCursor, keys, E4, nbucket);
    hipLaunchKernelGGL(bucket_gather_kernel, dim3(nbucket), dim3(256), 0, stream,
                       m, keys, bucketBase, w, b, (float*)d_out, N);
}